// Round 4
// baseline (89.630 us; speedup 1.0000x reference)
//
#include <hip/hip_runtime.h>
#include <hip/hip_bf16.h>

// Glow coupling layer, fused. rows N = 262144, C = 64.
// r2 = MLP_s2(x2); y1 = e(s2)*x1 + t2; r1 = MLP_s1(y1); y2 = e(s1)*x2 + t1.
//
// Round 4: LDS 32KB (h1/h2 only, everything else aliased/time-shared) for
// 4-5 blocks/CU; swizzled h layout ((r&7)<<4 byte-XOR) -> conflict-free b64
// writes; x1/x2 read straight from global in the combine phases; exp fused
// into the s-stash (waves 0-1) overlapped with x prefetch (waves 2-3).
//
// MFMA v_mfma_f32_16x16x32_bf16, swapped operands (W = A, act = B):
//   A frag: lane l holds A[row=l&15][k=(l>>4)*8+j]
//   B frag: lane l holds B[k=(l>>4)*8+j][col=l&15]
//   D     : lane l reg i -> (row/f = (l>>4)*4+i, col/r = l&15)  [m89/m91]

using bf16x8 = __attribute__((ext_vector_type(8))) short;
using f32x4  = __attribute__((ext_vector_type(4))) float;
using u32x2  = __attribute__((ext_vector_type(2))) unsigned int;

__device__ __forceinline__ unsigned short f2bf(float f) {
    unsigned int u = __float_as_uint(f);
    u += 0x7FFFu + ((u >> 16) & 1u);
    return (unsigned short)(u >> 16);
}
__device__ __forceinline__ unsigned int pk2bf(float a, float b) {
    union { __hip_bfloat162 h; unsigned int u; } cv;
    cv.h = __float22bfloat162_rn(float2{a, b});
    return cv.u;   // low16 = bf16(a), high16 = bf16(b)
}
__device__ __forceinline__ f32x4 mfma16(bf16x8 a, bf16x8 b, f32x4 c) {
    return __builtin_amdgcn_mfma_f32_16x16x32_bf16(a, b, c, 0, 0, 0);
}

// e(s) = exp(3.18*atan(s/5)) = exp2(4.5877702*atan(0.2 s)); deg-11 minimax.
__device__ __forceinline__ float e_fun(float s) {
    float z = 0.2f * s;
    float a = fabsf(z);
    float t = fminf(a, __builtin_amdgcn_rcpf(a));   // a<=1 ? a : 1/a
    float u = t * t;
    float p = -0.0537741f;
    p = fmaf(p, u,  0.2415614f);
    p = fmaf(p, u, -0.5341673f);
    p = fmaf(p, u,  0.8879339f);
    p = fmaf(p, u, -1.5260000f);
    p = fmaf(p, u,  4.5876659f);
    p = p * t;
    float r = (a > 1.0f) ? (7.2064613f - p) : p;    // K*pi/2 - p
    r = copysignf(r, s);
    return __builtin_amdgcn_exp2f(r);
}

// LDS map (32768 B total):
//   h1 region @ 0     (16384): swizzled h1 [64][256B]; sbuf f32[64][35] aliases
//   h2 region @ 16384 (16384): swizzled h2 [64][256B]; planes (hi@0,lo@4096)
//                              time-share [0:8192] (disjoint live ranges)
#define SBP 35          // sbuf f32 pitch: 35 = 3 mod 32 -> <=2-way scalar access

#define BIAS_OFF 114688           // 112 tiles * 1024B
#define WS_NEED  (114688 + 2560)

struct MlpW {
    bf16x8 wb1[2];
    bf16x8 wb2[2][4];
    bf16x8 wb3[4];
    f32x4  b1v[2], b2v[2], b3v;
};

// ---- fallback (MODE 0): convert weights per block ----
__device__ __forceinline__ bf16x8 load_wfrag(const float* __restrict__ W, int K, int frow, int k0) {
    const float4* p = reinterpret_cast<const float4*>(W + (size_t)frow * K + k0);
    float4 a = p[0], b = p[1];
    bf16x8 r;
    r[0] = (short)f2bf(a.x); r[1] = (short)f2bf(a.y);
    r[2] = (short)f2bf(a.z); r[3] = (short)f2bf(a.w);
    r[4] = (short)f2bf(b.x); r[5] = (short)f2bf(b.y);
    r[6] = (short)f2bf(b.z); r[7] = (short)f2bf(b.w);
    return r;
}
__device__ __forceinline__ void load_w_convert(
    const float* __restrict__ w1, const float* __restrict__ b1,
    const float* __restrict__ w2, const float* __restrict__ b2,
    const float* __restrict__ w3, const float* __restrict__ b3,
    int wave, int lane, MlpW& W)
{
    const int lr = lane & 15, lg = lane >> 4;
    #pragma unroll
    for (int f = 0; f < 2; ++f) {
        int ft = 2 * wave + f;
        W.wb1[f] = load_wfrag(w1, 32, 16 * ft + lr, lg * 8);
        W.b1v[f] = *reinterpret_cast<const f32x4*>(b1 + 16 * ft + 4 * lg);
        W.b2v[f] = *reinterpret_cast<const f32x4*>(b2 + 16 * ft + 4 * lg);
        #pragma unroll
        for (int ks = 0; ks < 4; ++ks)
            W.wb2[f][ks] = load_wfrag(w2, 128, 16 * ft + lr, 32 * ks + lg * 8);
    }
    #pragma unroll
    for (int ks = 0; ks < 4; ++ks)
        W.wb3[ks] = load_wfrag(w3, 128, 16 * wave + lr, 32 * ks + lg * 8);
    W.b3v = *reinterpret_cast<const f32x4*>(b3 + 16 * wave + 4 * lg);
}

// ---- prepped (MODE 1): straight uint4 loads from d_ws ----
__device__ __forceinline__ void load_w_prepped(const char* __restrict__ wsb,
                                               int mlp, int wave, int lane, MlpW& W)
{
    const int lg = lane >> 4;
    const uint4* base = reinterpret_cast<const uint4*>(wsb);
    union U { uint4 q; bf16x8 v; };
    #pragma unroll
    for (int f = 0; f < 2; ++f) {
        U u; u.q = base[(mlp * 56 + 2 * wave + f) * 64 + lane];
        W.wb1[f] = u.v;
        #pragma unroll
        for (int ks = 0; ks < 4; ++ks) {
            U u2; u2.q = base[(mlp * 56 + 8 + (2 * wave + f) * 4 + ks) * 64 + lane];
            W.wb2[f][ks] = u2.v;
        }
    }
    #pragma unroll
    for (int ks = 0; ks < 4; ++ks) {
        U u3; u3.q = base[(mlp * 56 + 40 + wave * 4 + ks) * 64 + lane];
        W.wb3[ks] = u3.v;
    }
    const float* bias = reinterpret_cast<const float*>(wsb + BIAS_OFF) + mlp * 320;
    #pragma unroll
    for (int f = 0; f < 2; ++f) {
        W.b1v[f] = *reinterpret_cast<const f32x4*>(bias + 16 * (2 * wave + f) + 4 * lg);
        W.b2v[f] = *reinterpret_cast<const f32x4*>(bias + 128 + 16 * (2 * wave + f) + 4 * lg);
    }
    W.b3v = *reinterpret_cast<const f32x4*>(bias + 256 + 16 * wave + 4 * lg);
}

// ---- 3-layer MLP, swapped operands: D[f][r] ----
// input planes (hi/lo bf16 [64][32] linear), h buffers swizzled [64][256B].
// rr[m][i] = r[f = 16*wave + 4*lg + i][row = 16*m + lr]
__device__ __forceinline__ void run_mlp(const MlpW& W,
    const unsigned short* __restrict__ hi, const unsigned short* __restrict__ lo,
    char* __restrict__ h1c, char* __restrict__ h2c,
    int wave, int lane, f32x4 (&rr)[4])
{
    const int lr = lane & 15, lg = lane >> 4;

    // layer 1: K=32, hi+lo planes
    #pragma unroll
    for (int m = 0; m < 4; ++m) {
        const int r = 16 * m + lr, sw = (r & 7) << 4;
        bf16x8 ah = *reinterpret_cast<const bf16x8*>(hi + r * 32 + lg * 8);
        bf16x8 al = *reinterpret_cast<const bf16x8*>(lo + r * 32 + lg * 8);
        #pragma unroll
        for (int f = 0; f < 2; ++f) {
            f32x4 acc = W.b1v[f];
            acc = mfma16(W.wb1[f], ah, acc);
            acc = mfma16(W.wb1[f], al, acc);
            unsigned int p0 = pk2bf(fmaxf(acc[0], 0.f), fmaxf(acc[1], 0.f));
            unsigned int p1 = pk2bf(fmaxf(acc[2], 0.f), fmaxf(acc[3], 0.f));
            const int bir = 32 * (2 * wave + f) + 8 * lg;
            *reinterpret_cast<u32x2*>(h1c + r * 256 + (bir ^ sw)) = u32x2{p0, p1};
        }
    }
    __syncthreads();

    // layer 2: K=128
    #pragma unroll
    for (int m = 0; m < 4; ++m) {
        const int r = 16 * m + lr, sw = (r & 7) << 4;
        bf16x8 hf[4];
        #pragma unroll
        for (int ks = 0; ks < 4; ++ks)
            hf[ks] = *reinterpret_cast<const bf16x8*>(h1c + r * 256 + ((64 * ks + 16 * lg) ^ sw));
        #pragma unroll
        for (int f = 0; f < 2; ++f) {
            f32x4 acc = W.b2v[f];
            #pragma unroll
            for (int ks = 0; ks < 4; ++ks)
                acc = mfma16(W.wb2[f][ks], hf[ks], acc);
            unsigned int p0 = pk2bf(fmaxf(acc[0], 0.f), fmaxf(acc[1], 0.f));
            unsigned int p1 = pk2bf(fmaxf(acc[2], 0.f), fmaxf(acc[3], 0.f));
            const int bir = 32 * (2 * wave + f) + 8 * lg;
            *reinterpret_cast<u32x2*>(h2c + r * 256 + (bir ^ sw)) = u32x2{p0, p1};
        }
    }
    __syncthreads();

    // layer 3: K=128, wave owns f-rows 16*wave..16*wave+15
    #pragma unroll
    for (int m = 0; m < 4; ++m) {
        const int r = 16 * m + lr, sw = (r & 7) << 4;
        f32x4 acc = W.b3v;
        #pragma unroll
        for (int ks = 0; ks < 4; ++ks) {
            bf16x8 hf = *reinterpret_cast<const bf16x8*>(h2c + r * 256 + ((64 * ks + 16 * lg) ^ sw));
            acc = mfma16(W.wb3[ks], hf, acc);
        }
        rr[m] = acc;
    }
}

// ---- weight prep ----
extern "C" __global__ void __launch_bounds__(256)
glow_prep(const float* __restrict__ s2w1, const float* __restrict__ s2w2,
          const float* __restrict__ s2w3, const float* __restrict__ s1w1,
          const float* __restrict__ s1w2, const float* __restrict__ s1w3,
          const float* __restrict__ s2b1, const float* __restrict__ s2b2,
          const float* __restrict__ s2b3, const float* __restrict__ s1b1,
          const float* __restrict__ s1b2, const float* __restrict__ s1b3,
          char* __restrict__ wsb)
{
    const int wave = threadIdx.x >> 6, lane = threadIdx.x & 63;
    const int lr = lane & 15, lg = lane >> 4;
    const int gw = blockIdx.x * 4 + wave;

    if (gw < 112) {
        int mlp = gw / 56, t = gw % 56;
        const float* Ws[2][3] = {{s2w1, s2w2, s2w3}, {s1w1, s1w2, s1w3}};
        const float* W; int K, row, k0;
        if (t < 8)       { W = Ws[mlp][0]; K = 32;  row = 16 * t + lr;          k0 = lg * 8; }
        else if (t < 40) { int u = t - 8;  W = Ws[mlp][1]; K = 128; row = 16 * (u >> 2) + lr; k0 = 32 * (u & 3) + lg * 8; }
        else             { int u = t - 40; W = Ws[mlp][2]; K = 128; row = 16 * (u >> 2) + lr; k0 = 32 * (u & 3) + lg * 8; }
        const float* p = W + (size_t)row * K + k0;
        union U { uint4 q; bf16x8 v; } u;
        #pragma unroll
        for (int j = 0; j < 8; ++j) u.v[j] = (short)f2bf(p[j]);
        reinterpret_cast<uint4*>(wsb)[gw * 64 + lane] = u.q;
    } else if (blockIdx.x == 28) {
        const float* Bs[6] = {s2b1, s2b2, s2b3, s1b1, s1b2, s1b3};
        const int sz[6] = {128, 128, 64, 128, 128, 64};
        float* dst = reinterpret_cast<float*>(wsb + BIAS_OFF);
        for (int i = threadIdx.x; i < 640; i += 256) {
            int j = i, a = 0;
            while (j >= sz[a]) { j -= sz[a]; ++a; }
            dst[i] = Bs[a][j];
        }
    }
}

template<int MODE>
__global__ void __launch_bounds__(256, 4)
glow_main(const float* __restrict__ x,
          const float* __restrict__ s1w1, const float* __restrict__ s1b1,
          const float* __restrict__ s1w2, const float* __restrict__ s1b2,
          const float* __restrict__ s1w3, const float* __restrict__ s1b3,
          const float* __restrict__ s2w1, const float* __restrict__ s2b1,
          const float* __restrict__ s2w2, const float* __restrict__ s2b2,
          const float* __restrict__ s2w3, const float* __restrict__ s2b3,
          const char* __restrict__ wsb, float* __restrict__ out)
{
    __shared__ __align__(16) char lds[32768];
    char* h1c = lds;
    char* h2c = lds + 16384;
    float*          sbuf = reinterpret_cast<float*>(lds);                 // alias h1
    unsigned short* phi  = reinterpret_cast<unsigned short*>(h2c);        // planes hi (time-shared)
    unsigned short* plo  = reinterpret_cast<unsigned short*>(h2c + 4096); // planes lo

    const int tid  = threadIdx.x;
    const int wave = tid >> 6, lane = tid & 63;
    const int lr = lane & 15, lg = lane >> 4;
    const size_t rowbase = (size_t)blockIdx.x * 64;

    // ---- Phase A: read x2 half only; write hi/lo bf16 planes ----
    #pragma unroll
    for (int it = 0; it < 2; ++it) {
        int chunk = it * 256 + tid;           // 512 chunks of 4 floats (64 rows x 8)
        int r = chunk >> 3, c4 = (chunk & 7) * 4;
        f32x4 v = *reinterpret_cast<const f32x4*>(x + (rowbase + r) * 64 + 32 + c4);
        unsigned int h0 = pk2bf(v[0], v[1]), h1p = pk2bf(v[2], v[3]);
        float f0 = __uint_as_float(h0 << 16);
        float f1 = __uint_as_float(h0 & 0xFFFF0000u);
        float f2 = __uint_as_float(h1p << 16);
        float f3 = __uint_as_float(h1p & 0xFFFF0000u);
        unsigned int l0 = pk2bf(v[0] - f0, v[1] - f1);
        unsigned int l1 = pk2bf(v[2] - f2, v[3] - f3);
        *reinterpret_cast<u32x2*>(phi + r * 32 + c4) = u32x2{h0, h1p};
        *reinterpret_cast<u32x2*>(plo + r * 32 + c4) = u32x2{l0, l1};
    }

    MlpW W;
    if (MODE) load_w_prepped(wsb, 0, wave, lane, W);
    else      load_w_convert(s2w1, s2b1, s2w2, s2b2, s2w3, s2b3, wave, lane, W);
    __syncthreads();

    f32x4 rr[4];

    // ---- MLP s2 on x2 (planes2 consumed in L1; h2 overwrites them in L2) ----
    run_mlp(W, phi, plo, h1c, h2c, wave, lane, rr);

    // prefetch s1 weights
    if (MODE) load_w_prepped(wsb, 1, wave, lane, W);
    else      load_w_convert(s1w1, s1b1, s1w2, s1b2, s1w3, s1b3, wave, lane, W);

    // ---- epilogue 1: w01 store e(s2) to sbuf; w23 prefetch x1 ----
    f32x4 xv[4];
    if (wave < 2) {
        #pragma unroll
        for (int m = 0; m < 4; ++m) {
            const int r = 16 * m + lr;
            #pragma unroll
            for (int i = 0; i < 4; ++i)
                sbuf[r * SBP + 16 * wave + 4 * lg + i] = e_fun(rr[m][i]);
        }
    } else {
        #pragma unroll
        for (int m = 0; m < 4; ++m)
            xv[m] = *reinterpret_cast<const f32x4*>(
                x + (rowbase + 16 * m + lr) * 64 + 16 * (wave - 2) + 4 * lg);
    }
    __syncthreads();

    // w23: y1 = e*x1 + t2 -> out, + y1 hi/lo planes (h2[0:8192], dead now)
    if (wave >= 2) {
        const int c = 16 * (wave - 2) + 4 * lg;
        #pragma unroll
        for (int m = 0; m < 4; ++m) {
            const int r = 16 * m + lr;
            f32x4 y;
            #pragma unroll
            for (int i = 0; i < 4; ++i)
                y[i] = fmaf(sbuf[r * SBP + c + i], xv[m][i], rr[m][i]);
            *reinterpret_cast<f32x4*>(out + (rowbase + r) * 64 + c) = y;
            unsigned int h0 = pk2bf(y[0], y[1]), h1p = pk2bf(y[2], y[3]);
            float f0 = __uint_as_float(h0 << 16);
            float f1 = __uint_as_float(h0 & 0xFFFF0000u);
            float f2 = __uint_as_float(h1p << 16);
            float f3 = __uint_as_float(h1p & 0xFFFF0000u);
            unsigned int l0 = pk2bf(y[0] - f0, y[1] - f1);
            unsigned int l1 = pk2bf(y[2] - f2, y[3] - f3);
            *reinterpret_cast<u32x2*>(phi + r * 32 + c) = u32x2{h0, h1p};
            *reinterpret_cast<u32x2*>(plo + r * 32 + c) = u32x2{l0, l1};
        }
    }
    __syncthreads();

    // ---- MLP s1 on y1 ----
    run_mlp(W, phi, plo, h1c, h2c, wave, lane, rr);

    // ---- epilogue 2: w01 store e(s1); w23 prefetch x2; y2 = e*x2 + t1 ----
    if (wave < 2) {
        #pragma unroll
        for (int m = 0; m < 4; ++m) {
            const int r = 16 * m + lr;
            #pragma unroll
            for (int i = 0; i < 4; ++i)
                sbuf[r * SBP + 16 * wave + 4 * lg + i] = e_fun(rr[m][i]);
        }
    } else {
        #pragma unroll
        for (int m = 0; m < 4; ++m)
            xv[m] = *reinterpret_cast<const f32x4*>(
                x + (rowbase + 16 * m + lr) * 64 + 32 + 16 * (wave - 2) + 4 * lg);
    }
    __syncthreads();

    if (wave >= 2) {
        const int c = 16 * (wave - 2) + 4 * lg;
        #pragma unroll
        for (int m = 0; m < 4; ++m) {
            const int r = 16 * m + lr;
            f32x4 y;
            #pragma unroll
            for (int i = 0; i < 4; ++i)
                y[i] = fmaf(sbuf[r * SBP + c + i], xv[m][i], rr[m][i]);
            *reinterpret_cast<f32x4*>(out + (rowbase + r) * 64 + 32 + c) = y;
        }
    }
}

extern "C" void kernel_launch(void* const* d_in, const int* in_sizes, int n_in,
                              void* d_out, int out_size, void* d_ws, size_t ws_size,
                              hipStream_t stream) {
    const float* x    = (const float*)d_in[0];
    const float* s1w1 = (const float*)d_in[1];
    const float* s1b1 = (const float*)d_in[2];
    const float* s1w2 = (const float*)d_in[3];
    const float* s1b2 = (const float*)d_in[4];
    const float* s1w3 = (const float*)d_in[5];
    const float* s1b3 = (const float*)d_in[6];
    const float* s2w1 = (const float*)d_in[7];
    const float* s2b1 = (const float*)d_in[8];
    const float* s2w2 = (const float*)d_in[9];
    const float* s2b2 = (const float*)d_in[10];
    const float* s2w3 = (const float*)d_in[11];
    const float* s2b3 = (const float*)d_in[12];
    float* out = (float*)d_out;
    char* wsb  = (char*)d_ws;

    int nrows   = in_sizes[0] / 64;   // 262144
    int nblocks = nrows / 64;         // 4096

    if (ws_size >= (size_t)WS_NEED) {
        hipLaunchKernelGGL(glow_prep, dim3(29), dim3(256), 0, stream,
                           s2w1, s2w2, s2w3, s1w1, s1w2, s1w3,
                           s2b1, s2b2, s2b3, s1b1, s1b2, s1b3, wsb);
        hipLaunchKernelGGL((glow_main<1>), dim3(nblocks), dim3(256), 0, stream,
                           x, s1w1, s1b1, s1w2, s1b2, s1w3, s1b3,
                           s2w1, s2b1, s2w2, s2b2, s2w3, s2b3, wsb, out);
    } else {
        hipLaunchKernelGGL((glow_main<0>), dim3(nblocks), dim3(256), 0, stream,
                           x, s1w1, s1b1, s1w2, s1b2, s1w3, s1b3,
                           s2w1, s2b1, s2w2, s2b2, s2w3, s2b3, wsb, out);
    }
}

// Round 5
// 72.158 us; speedup vs baseline: 1.2421x; 1.2421x over previous
//
#include <hip/hip_runtime.h>
#include <hip/hip_bf16.h>

// Glow coupling layer, fused. rows N = 262144, C = 64.
// r2 = MLP_s2(x2); y1 = e(s2)*x1 + t2; r1 = MLP_s1(y1); y2 = e(s1)*x2 + t1.
//
// Round 5: in-register epilogues. W3 rows permuted so wave w owns features
// {8w..8w+7, 32+8w..32+8w+7}: s/t pairing via one __shfl_xor(.,32) -> no
// sbuf, 7 barriers. x read ONCE (xv2 held in regs; xv1 loaded pre-L3).
// Weights JIT per layer (peak frag regs 48). launch_bounds(256,3): no spill.
// h linear HP=136 (b128 structurally balanced), planes pitch 40.
//
// MFMA v_mfma_f32_16x16x32_bf16, W = A-operand, activations = B-operand:
//   A frag: lane l holds A[row=l&15][k=(l>>4)*8+j]
//   B frag: lane l holds B[k=(l>>4)*8+j][col=l&15]
//   D     : lane l reg i -> (feat-row = (l>>4)*4+i, col = l&15)  [m89/m91]

using bf16x8 = __attribute__((ext_vector_type(8))) short;
using f32x4  = __attribute__((ext_vector_type(4))) float;
using u32x2  = __attribute__((ext_vector_type(2))) unsigned int;

__device__ __forceinline__ unsigned short f2bf(float f) {
    unsigned int u = __float_as_uint(f);
    u += 0x7FFFu + ((u >> 16) & 1u);
    return (unsigned short)(u >> 16);
}
__device__ __forceinline__ unsigned int pk2bf(float a, float b) {
    union { __hip_bfloat162 h; unsigned int u; } cv;
    cv.h = __float22bfloat162_rn(float2{a, b});
    return cv.u;   // low16 = bf16(a), high16 = bf16(b)
}
__device__ __forceinline__ float lo16f(unsigned int u) { return __uint_as_float(u << 16); }
__device__ __forceinline__ float hi16f(unsigned int u) { return __uint_as_float(u & 0xFFFF0000u); }

__device__ __forceinline__ f32x4 mfma16(bf16x8 a, bf16x8 b, f32x4 c) {
    return __builtin_amdgcn_mfma_f32_16x16x32_bf16(a, b, c, 0, 0, 0);
}

// e(s) = exp(3.18*atan(s/5)) = exp2(4.5877702*atan(0.2 s)); deg-11 minimax.
__device__ __forceinline__ float e_fun(float s) {
    float z = 0.2f * s;
    float a = fabsf(z);
    float t = fminf(a, __builtin_amdgcn_rcpf(a));   // a<=1 ? a : 1/a
    float u = t * t;
    float p = -0.0537741f;
    p = fmaf(p, u,  0.2415614f);
    p = fmaf(p, u, -0.5341673f);
    p = fmaf(p, u,  0.8879339f);
    p = fmaf(p, u, -1.5260000f);
    p = fmaf(p, u,  4.5876659f);
    p = p * t;
    float r = (a > 1.0f) ? (7.2064613f - p) : p;    // K*pi/2 - p
    r = copysignf(r, s);
    return __builtin_amdgcn_exp2f(r);
}

// W3 feature permutation: wave w, frag row fr -> feature
__device__ __forceinline__ int feat3(int w, int fr) {
    return fr < 8 ? 8 * w + fr : 24 + 8 * w + fr;   // {8w..8w+7, 32+8w..32+8w+7}
}

#define HP  136   // h pitch (shorts): 272B rows, b128 reads bank-balanced
#define PP  40    // planes pitch (shorts): 80B rows

// LDS: h1 [64][272B] @0 (17408); h2 [64][272B] @17408 (17408).
// planes (hi 5120 + lo 5120) time-share h2[0:10240].
#define LDS_BYTES 34816

#define BIAS_OFF 114688           // 112 tiles * 1024B
#define WS_NEED  (114688 + 2560)

struct WPtrs { const float *w1, *b1, *w2, *b2, *w3, *b3; };

__device__ __forceinline__ bf16x8 load_wfrag(const float* __restrict__ W, int K, int frow, int k0) {
    const float4* p = reinterpret_cast<const float4*>(W + (size_t)frow * K + k0);
    float4 a = p[0], b = p[1];
    bf16x8 r;
    r[0] = (short)f2bf(a.x); r[1] = (short)f2bf(a.y);
    r[2] = (short)f2bf(a.z); r[3] = (short)f2bf(a.w);
    r[4] = (short)f2bf(b.x); r[5] = (short)f2bf(b.y);
    r[6] = (short)f2bf(b.z); r[7] = (short)f2bf(b.w);
    return r;
}

template<int MODE>
__device__ __forceinline__ bf16x8 get_frag(const char* wsb, const WPtrs& P, int mlp,
                                           int tile, int which, int row, int k0, int lane) {
    if constexpr (MODE != 0) {
        union { uint4 q; bf16x8 v; } u;
        u.q = reinterpret_cast<const uint4*>(wsb)[(mlp * 56 + tile) * 64 + lane];
        return u.v;
    } else {
        const float* W = (which == 0) ? P.w1 : (which == 1) ? P.w2 : P.w3;
        return load_wfrag(W, (which == 0) ? 32 : 128, row, k0);
    }
}

// ---- MLP layers 1-2 (contains the two internal barriers) ----
template<int MODE>
__device__ __forceinline__ void mlp_L12(const char* wsb, const WPtrs& P, int mlp,
    const unsigned short* __restrict__ phi, const unsigned short* __restrict__ plo,
    unsigned short* __restrict__ h1, unsigned short* __restrict__ h2,
    int wave, int lane)
{
    const int lr = lane & 15, lg = lane >> 4;

    bf16x8 wb1[2], wb2[2][4];
    f32x4 b1v[2], b2v[2];
    #pragma unroll
    for (int f = 0; f < 2; ++f) {
        const int ft = 2 * wave + f;
        wb1[f] = get_frag<MODE>(wsb, P, mlp, ft, 0, 16 * ft + lr, 8 * lg, lane);
        #pragma unroll
        for (int ks = 0; ks < 4; ++ks)
            wb2[f][ks] = get_frag<MODE>(wsb, P, mlp, 8 + ft * 4 + ks, 1,
                                        16 * ft + lr, 32 * ks + 8 * lg, lane);
        if (MODE) {
            const float* bias = reinterpret_cast<const float*>(wsb + BIAS_OFF) + mlp * 320;
            b1v[f] = *reinterpret_cast<const f32x4*>(bias + 16 * ft + 4 * lg);
            b2v[f] = *reinterpret_cast<const f32x4*>(bias + 128 + 16 * ft + 4 * lg);
        } else {
            b1v[f] = *reinterpret_cast<const f32x4*>(P.b1 + 16 * ft + 4 * lg);
            b2v[f] = *reinterpret_cast<const f32x4*>(P.b2 + 16 * ft + 4 * lg);
        }
    }

    // layer 1: K=32, hi+lo planes
    #pragma unroll
    for (int m = 0; m < 4; ++m) {
        const int r = 16 * m + lr;
        bf16x8 ah = *reinterpret_cast<const bf16x8*>(phi + r * PP + 8 * lg);
        bf16x8 al = *reinterpret_cast<const bf16x8*>(plo + r * PP + 8 * lg);
        #pragma unroll
        for (int f = 0; f < 2; ++f) {
            f32x4 acc = b1v[f];
            acc = mfma16(wb1[f], ah, acc);
            acc = mfma16(wb1[f], al, acc);
            unsigned int p0 = pk2bf(fmaxf(acc[0], 0.f), fmaxf(acc[1], 0.f));
            unsigned int p1 = pk2bf(fmaxf(acc[2], 0.f), fmaxf(acc[3], 0.f));
            *reinterpret_cast<u32x2*>(h1 + r * HP + 16 * (2 * wave + f) + 4 * lg) = u32x2{p0, p1};
        }
    }
    __syncthreads();

    // layer 2: K=128
    #pragma unroll
    for (int m = 0; m < 4; ++m) {
        const int r = 16 * m + lr;
        bf16x8 hf[4];
        #pragma unroll
        for (int ks = 0; ks < 4; ++ks)
            hf[ks] = *reinterpret_cast<const bf16x8*>(h1 + r * HP + 32 * ks + 8 * lg);
        #pragma unroll
        for (int f = 0; f < 2; ++f) {
            f32x4 acc = b2v[f];
            #pragma unroll
            for (int ks = 0; ks < 4; ++ks)
                acc = mfma16(wb2[f][ks], hf[ks], acc);
            unsigned int p0 = pk2bf(fmaxf(acc[0], 0.f), fmaxf(acc[1], 0.f));
            unsigned int p1 = pk2bf(fmaxf(acc[2], 0.f), fmaxf(acc[3], 0.f));
            *reinterpret_cast<u32x2*>(h2 + r * HP + 16 * (2 * wave + f) + 4 * lg) = u32x2{p0, p1};
        }
    }
    __syncthreads();
}

// ---- MLP layer 3 (permuted features) ----
template<int MODE>
__device__ __forceinline__ void mlp_L3(const char* wsb, const WPtrs& P, int mlp,
    const unsigned short* __restrict__ h2, int wave, int lane, f32x4 (&rr)[4])
{
    const int lr = lane & 15, lg = lane >> 4;

    bf16x8 wb3[4];
    #pragma unroll
    for (int ks = 0; ks < 4; ++ks)
        wb3[ks] = get_frag<MODE>(wsb, P, mlp, 40 + 4 * wave + ks, 2,
                                 feat3(wave, lr), 32 * ks + 8 * lg, lane);
    f32x4 b3v;
    if (MODE) {
        const float* bias = reinterpret_cast<const float*>(wsb + BIAS_OFF) + mlp * 320;
        b3v = *reinterpret_cast<const f32x4*>(bias + 256 + 16 * wave + 4 * lg);
    } else {
        const int base = (lg < 2) ? (8 * wave + 4 * lg) : (24 + 8 * wave + 4 * lg);
        b3v = *reinterpret_cast<const f32x4*>(P.b3 + base);
    }

    #pragma unroll
    for (int m = 0; m < 4; ++m) {
        const int r = 16 * m + lr;
        f32x4 acc = b3v;
        #pragma unroll
        for (int ks = 0; ks < 4; ++ks) {
            bf16x8 hf = *reinterpret_cast<const bf16x8*>(h2 + r * HP + 32 * ks + 8 * lg);
            acc = mfma16(wb3[ks], hf, acc);
        }
        rr[m] = acc;
    }
}

// ---- in-register epilogue ----
// rr[m][i] = r3[feat3(wave, 4lg+i)][16m+lr]; xv[m][i] = x[.][cbase+8w+4(lg&1)+i]
__device__ __forceinline__ void epilogue(const f32x4 (&rr)[4], const f32x4 (&xv)[4],
    float* __restrict__ out, size_t rowbase, int cbase,
    int wave, int lane, bool write_planes,
    unsigned short* __restrict__ phi, unsigned short* __restrict__ plo)
{
    const int lr = lane & 15, lg = lane >> 4;
    const bool shalf = (lg < 2);
    const int c = cbase + 8 * wave + 4 * (lg & 1);

    #pragma unroll
    for (int m = 0; m < 4; ++m) {
        const int r = 16 * m + lr;
        f32x4 y;
        #pragma unroll
        for (int i = 0; i < 4; ++i) {
            float sw = __shfl_xor(rr[m][i], 32, 64);
            float sv = shalf ? rr[m][i] : sw;
            float tv = shalf ? sw : rr[m][i];
            y[i] = fmaf(e_fun(sv), xv[m][i], tv);
        }
        if (shalf) {
            *reinterpret_cast<f32x4*>(out + (rowbase + r) * 64 + c) = y;
            if (write_planes) {
                unsigned int h0 = pk2bf(y[0], y[1]), h1p = pk2bf(y[2], y[3]);
                unsigned int l0 = pk2bf(y[0] - lo16f(h0),  y[1] - hi16f(h0));
                unsigned int l1 = pk2bf(y[2] - lo16f(h1p), y[3] - hi16f(h1p));
                const int po = r * PP + 8 * wave + 4 * lg;
                *reinterpret_cast<u32x2*>(phi + po) = u32x2{h0, h1p};
                *reinterpret_cast<u32x2*>(plo + po) = u32x2{l0, l1};
            }
        }
    }
}

// ---- weight prep: fragment tiles + biases (b3 permuted) into d_ws ----
extern "C" __global__ void __launch_bounds__(256)
glow_prep(const float* __restrict__ s2w1, const float* __restrict__ s2w2,
          const float* __restrict__ s2w3, const float* __restrict__ s1w1,
          const float* __restrict__ s1w2, const float* __restrict__ s1w3,
          const float* __restrict__ s2b1, const float* __restrict__ s2b2,
          const float* __restrict__ s2b3, const float* __restrict__ s1b1,
          const float* __restrict__ s1b2, const float* __restrict__ s1b3,
          char* __restrict__ wsb)
{
    const int wave = threadIdx.x >> 6, lane = threadIdx.x & 63;
    const int lr = lane & 15, lg = lane >> 4;
    const int gw = blockIdx.x * 4 + wave;

    if (gw < 112) {
        int mlp = gw / 56, t = gw % 56;
        const float* Ws[2][3] = {{s2w1, s2w2, s2w3}, {s1w1, s1w2, s1w3}};
        const float* W; int K, row, k0;
        if (t < 8)       { W = Ws[mlp][0]; K = 32;  row = 16 * t + lr;           k0 = lg * 8; }
        else if (t < 40) { int u = t - 8;  W = Ws[mlp][1]; K = 128; row = 16 * (u >> 2) + lr;  k0 = 32 * (u & 3) + lg * 8; }
        else             { int u = t - 40; W = Ws[mlp][2]; K = 128; row = feat3(u >> 2, lr);   k0 = 32 * (u & 3) + lg * 8; }
        const float* p = W + (size_t)row * K + k0;
        union U { uint4 q; bf16x8 v; } u;
        #pragma unroll
        for (int j = 0; j < 8; ++j) u.v[j] = (short)f2bf(p[j]);
        reinterpret_cast<uint4*>(wsb)[gw * 64 + lane] = u.q;
    } else if (blockIdx.x == 28) {
        const float* Bs[2][3] = {{s2b1, s2b2, s2b3}, {s1b1, s1b2, s1b3}};
        float* dst = reinterpret_cast<float*>(wsb + BIAS_OFF);
        for (int i = threadIdx.x; i < 640; i += 256) {
            int mlp = i / 320, j = i % 320;
            float v;
            if (j < 128)      v = Bs[mlp][0][j];
            else if (j < 256) v = Bs[mlp][1][j - 128];
            else { int k = j - 256; v = Bs[mlp][2][feat3(k >> 4, k & 15)]; }
            dst[i] = v;
        }
    }
}

template<int MODE>
__global__ void __launch_bounds__(256, 3)
glow_main(const float* __restrict__ x,
          const float* __restrict__ s1w1, const float* __restrict__ s1b1,
          const float* __restrict__ s1w2, const float* __restrict__ s1b2,
          const float* __restrict__ s1w3, const float* __restrict__ s1b3,
          const float* __restrict__ s2w1, const float* __restrict__ s2b1,
          const float* __restrict__ s2w2, const float* __restrict__ s2b2,
          const float* __restrict__ s2w3, const float* __restrict__ s2b3,
          const char* __restrict__ wsb, float* __restrict__ out)
{
    __shared__ __align__(16) char lds[LDS_BYTES];
    unsigned short* h1  = reinterpret_cast<unsigned short*>(lds);
    unsigned short* h2  = reinterpret_cast<unsigned short*>(lds + 17408);
    unsigned short* phi = reinterpret_cast<unsigned short*>(lds + 17408);        // time-share h2
    unsigned short* plo = reinterpret_cast<unsigned short*>(lds + 17408 + 5120);

    const int tid  = threadIdx.x;
    const int wave = tid >> 6, lane = tid & 63;
    const int lr = lane & 15, lg = lane >> 4, half = lg & 1;
    const size_t rowbase = (size_t)blockIdx.x * 64;

    const WPtrs P[2] = {{s2w1, s2b1, s2w2, s2b2, s2w3, s2b3},
                        {s1w1, s1b1, s1w2, s1b2, s1w3, s1b3}};

    // ---- Phase A: load x2 into regs (held to end); lg<2 writes x2 planes ----
    f32x4 xv2[4];
    #pragma unroll
    for (int m = 0; m < 4; ++m)
        xv2[m] = *reinterpret_cast<const f32x4*>(
            x + (rowbase + 16 * m + lr) * 64 + 32 + 8 * wave + 4 * half);
    if (lg < 2) {
        #pragma unroll
        for (int m = 0; m < 4; ++m) {
            const int r = 16 * m + lr;
            unsigned int h0 = pk2bf(xv2[m][0], xv2[m][1]), h1p = pk2bf(xv2[m][2], xv2[m][3]);
            unsigned int l0 = pk2bf(xv2[m][0] - lo16f(h0),  xv2[m][1] - hi16f(h0));
            unsigned int l1 = pk2bf(xv2[m][2] - lo16f(h1p), xv2[m][3] - hi16f(h1p));
            const int po = r * PP + 8 * wave + 4 * lg;
            *reinterpret_cast<u32x2*>(phi + po) = u32x2{h0, h1p};
            *reinterpret_cast<u32x2*>(plo + po) = u32x2{l0, l1};
        }
    }
    __syncthreads();                                   // (1)

    f32x4 rr[4];

    // ---- MLP s2 on x2 ----
    mlp_L12<MODE>(wsb, P[0], 0, phi, plo, h1, h2, wave, lane);   // barriers (2),(3)
    f32x4 xv1[4];                                      // x1 load hides under L3
    #pragma unroll
    for (int m = 0; m < 4; ++m)
        xv1[m] = *reinterpret_cast<const f32x4*>(
            x + (rowbase + 16 * m + lr) * 64 + 8 * wave + 4 * half);
    mlp_L3<MODE>(wsb, P[0], 0, h2, wave, lane, rr);
    __syncthreads();                                   // (4) h2 reads done before planes overwrite

    // ---- epilogue 1: y1 = e(s2)*x1 + t2 -> out cols 0..31 + y1 planes ----
    epilogue(rr, xv1, out, rowbase, 0, wave, lane, true, phi, plo);
    __syncthreads();                                   // (5)

    // ---- MLP s1 on y1 ----
    mlp_L12<MODE>(wsb, P[1], 1, phi, plo, h1, h2, wave, lane);   // barriers (6),(7)
    mlp_L3<MODE>(wsb, P[1], 1, h2, wave, lane, rr);

    // ---- epilogue 2: y2 = e(s1)*x2 + t1 -> out cols 32..63 (no LDS) ----
    epilogue(rr, xv2, out, rowbase, 32, wave, lane, false, phi, plo);
}

extern "C" void kernel_launch(void* const* d_in, const int* in_sizes, int n_in,
                              void* d_out, int out_size, void* d_ws, size_t ws_size,
                              hipStream_t stream) {
    const float* x    = (const float*)d_in[0];
    const float* s1w1 = (const float*)d_in[1];
    const float* s1b1 = (const float*)d_in[2];
    const float* s1w2 = (const float*)d_in[3];
    const float* s1b2 = (const float*)d_in[4];
    const float* s1w3 = (const float*)d_in[5];
    const float* s1b3 = (const float*)d_in[6];
    const float* s2w1 = (const float*)d_in[7];
    const float* s2b1 = (const float*)d_in[8];
    const float* s2w2 = (const float*)d_in[9];
    const float* s2b2 = (const float*)d_in[10];
    const float* s2w3 = (const float*)d_in[11];
    const float* s2b3 = (const float*)d_in[12];
    float* out = (float*)d_out;
    char* wsb  = (char*)d_ws;

    int nrows   = in_sizes[0] / 64;   // 262144
    int nblocks = nrows / 64;         // 4096

    if (ws_size >= (size_t)WS_NEED) {
        hipLaunchKernelGGL(glow_prep, dim3(29), dim3(256), 0, stream,
                           s2w1, s2w2, s2w3, s1w1, s1w2, s1w3,
                           s2b1, s2b2, s2b3, s1b1, s1b2, s1b3, wsb);
        hipLaunchKernelGGL((glow_main<1>), dim3(nblocks), dim3(256), 0, stream,
                           x, s1w1, s1b1, s1w2, s1b2, s1w3, s1b3,
                           s2w1, s2b1, s2w2, s2b2, s2w3, s2b3, wsb, out);
    } else {
        hipLaunchKernelGGL((glow_main<0>), dim3(nblocks), dim3(256), 0, stream,
                           x, s1w1, s1b1, s1w2, s1b2, s1w3, s1b3,
                           s2w1, s2b1, s2w2, s2b2, s2w3, s2b3, wsb, out);
    }
}